// Round 18
// baseline (52.250 us; speedup 1.0000x reference)
//
#include <hip/hip_runtime.h>

// vol [2,160,192,160,1] f32, trf [2,160,192,160,3] f32
constexpr int B = 2, X = 160, Y = 192, Z = 160;
constexpr int TXs = 16, TYs = 16, TZs = 16;              // output tile (4096 voxels)
constexpr int XT = X / TXs, YT = Y / TYs, ZT = Z / TZs;  // 10, 12, 10
constexpr int NTILES = B * XT * YT * ZT;                 // 2400, divisible by 8
constexpr int NXCD = 8;
constexpr int CHUNK = NTILES / NXCD;                     // 300
// staged region: x halo -4/+3 (23), y halo +-4 (24), z halo +-8 (32)
// layout: [row = ux*24+uy][uz], row stride 33 words.
// staging: 8 f32x4 chunks/row -> write bank = row+4j+i exactly 2-way (free).
constexpr int RX = 23, RY = 24, RZ = 32;
constexpr int RSTRIDE = 33;
constexpr int NROWS = RX * RY;                           // 552
constexpr int LDSF = NROWS * RSTRIDE;                    // 18216 words
constexpr int LDSB = LDSF * 4;                           // 72864 B -> 2 blocks/CU
constexpr int NCHUNKS = NROWS * 8;                       // 4416 f32x4 staging chunks

typedef float f32x4 __attribute__((ext_vector_type(4)));
typedef float f32x2a __attribute__((ext_vector_type(2), aligned(4)));

__global__ __launch_bounds__(1024, 8) void warp_kernel(
    const float* __restrict__ vol,
    const float* __restrict__ trf,
    float* __restrict__ out)
{
    extern __shared__ float lds[];

    const int tid = threadIdx.x;
    const int bid = blockIdx.x;

    // XCD-chunked bijective swizzle (NTILES % 8 == 0)
    const int eff = (bid & (NXCD - 1)) * CHUNK + (bid >> 3);

    int tz = eff % ZT;
    int r  = eff / ZT;
    int ty = r % YT;
    int r2 = r / YT;
    int tx = r2 % XT;
    int b  = r2 / XT;

    const int xs = tx * TXs - 4;       // region x origin (23 wide: -4..+18)
    const int ys = ty * TYs - 4;       // region y origin (24 wide)
    const int zs = tz * TZs - 8;       // region z origin (32 wide, multiple of 4)
    const int bX = b * X;

    // ---- stage vol region into LDS ----
    // chunk c in [0,4416): row = c>>3 (ux=row/24, uy=row%24), j = c&7,
    // z = zs+4j; LDS words row*33 + 4j .. +3.
    // 1024 threads: 4 full passes + 1 guarded (tid<320). Pass stride 128 rows
    // = (+5 ux, +8 uy) with wrap.
    {
        int row0 = tid >> 3;           // 0..127
        int j    = tid & 7;
        bool interior = (xs >= 0) & (xs + RX <= X) &
                        (ys >= 0) & (ys + RY <= Y) &
                        (zs >= 0) & (zs + RZ <= Z);
        if (interior) {
            unsigned ux = (unsigned)row0 / 24u;
            int      uy = row0 - 24 * (int)ux;
            const float* gp = vol +
                ((size_t)(bX + xs + (int)ux) * Y + (ys + uy)) * Z + (zs + 4 * j);
            int a = row0 * RSTRIDE + 4 * j;
#pragma unroll
            for (int k = 0; k < 5; ++k) {
                if (k < 4 || tid < NCHUNKS - 4096) {
                    f32x4 v = *reinterpret_cast<const f32x4*>(gp);
                    *reinterpret_cast<f32x4*>(&lds[a]) = v;   // 16B-aligned (a = row*33+4j? row*33 odd!)
                }
                int uyn = uy + 8;
                bool wrap = (uyn >= 24);
                gp += wrap ? (size_t)(6 * Y - 16) * Z : (size_t)(5 * Y + 8) * Z;
                uy  = wrap ? uyn - 24 : uyn;
                a  += 128 * RSTRIDE;
            }
        } else {
#pragma unroll
            for (int k = 0; k < 5; ++k) {
                int c = tid + k * 1024;
                if (c < NCHUNKS) {
                    int row = c >> 3;
                    int jj  = c & 7;
                    unsigned ux = (unsigned)row / 24u;
                    int      uy = row - 24 * (int)ux;
                    int xg = min(max(xs + (int)ux, 0), X - 1);
                    int yg = min(max(ys + uy, 0), Y - 1);
                    int zg = min(max(zs + 4 * jj, 0), Z - 4);
                    const f32x4 v = *reinterpret_cast<const f32x4*>(
                        vol + ((size_t)(bX + xg) * Y + yg) * Z + zg);
                    int a = row * RSTRIDE + 4 * jj;
                    lds[a + 0] = v.x;
                    lds[a + 1] = v.y;
                    lds[a + 2] = v.z;
                    lds[a + 3] = v.w;
                }
            }
        }
    }
    __syncthreads();

    // ---- this thread's 4 voxels: (x, y, z0v..z0v+3) ----
    int zq = tid & 3;
    int ly = (tid >> 2) & 15;
    int lx = tid >> 6;
    int x  = tx * TXs + lx;
    int y  = ty * TYs + ly;
    int z0v = tz * TZs + 4 * zq;

    size_t vid0 = ((size_t)(bX + x) * Y + y) * Z + z0v;

    // 12 trf floats (4 voxels x 3), 48B, 16B-aligned
    const f32x4* tp = reinterpret_cast<const f32x4*>(trf + vid0 * 3);
    f32x4 t0 = tp[0], t1 = tp[1], t2 = tp[2];
    float d[12] = {t0.x, t0.y, t0.z, t0.w,
                   t1.x, t1.y, t1.z, t1.w,
                   t2.x, t2.y, t2.z, t2.w};

    // med3 shift-invariance: clip(g+disp,0,max)-origin
    //   = med3(local+disp, -origin, max-origin), local = g - origin.
    const float c0x = (float)(-xs), c1x = (float)(X - 1 - xs);
    const float c0y = (float)(-ys), c1y = (float)(Y - 1 - ys);
    const float c0z = (float)(-zs), c1z = (float)(Z - 1 - zs);
    const float fxL = (float)(lx + 4);       // x - xs
    const float fyL = (float)(ly + 4);       // y - ys
    const float fzL = (float)(4 * zq + 8);   // z0v - zs

    float res[4];
#pragma unroll
    for (int e = 0; e < 4; ++e) {
        float rxf = __builtin_amdgcn_fmed3f(fxL + d[3 * e + 0], c0x, c1x);
        float ryf = __builtin_amdgcn_fmed3f(fyL + d[3 * e + 1], c0y, c1y);
        float rzf = __builtin_amdgcn_fmed3f((fzL + (float)e) + d[3 * e + 2], c0z, c1z);

        float flx = floorf(rxf), fly = floorf(ryf), flz = floorf(rzf);
        int ux0 = (int)flx, uy0 = (int)fly, uz0 = (int)flz;
        float fx = rxf - flx, fy = ryf - fly, fz = rzf - flz;

        bool ok = ((unsigned)ux0 < (unsigned)(RX - 1)) &
                  ((unsigned)uy0 < (unsigned)(RY - 1)) &
                  ((unsigned)uz0 < (unsigned)(RZ - 1));

        float v000, v001, v010, v011, v100, v101, v110, v111;
        if (ok) {
            // one base; corners at word offsets {0, 33 (+y), 792 (+x), 825}
            int w = (ux0 * 24 + uy0) * RSTRIDE + uz0;
            f32x2a p00 = *reinterpret_cast<const f32x2a*>(&lds[w]);
            f32x2a p01 = *reinterpret_cast<const f32x2a*>(&lds[w + RSTRIDE]);
            f32x2a p10 = *reinterpret_cast<const f32x2a*>(&lds[w + 24 * RSTRIDE]);
            f32x2a p11 = *reinterpret_cast<const f32x2a*>(&lds[w + 25 * RSTRIDE]);
            v000 = p00.x; v001 = p00.y;
            v010 = p01.x; v011 = p01.y;
            v100 = p10.x; v101 = p10.y;
            v110 = p11.x; v111 = p11.y;
        } else {
            int ix0 = ux0 + xs, iy0 = uy0 + ys, iz0 = uz0 + zs;
            ix0 = min(max(ix0, 0), X - 1);
            iy0 = min(max(iy0, 0), Y - 1);
            iz0 = min(max(iz0, 0), Z - 1);
            int ix1 = min(ix0 + 1, X - 1);
            int iy1 = min(iy0 + 1, Y - 1);
            int iz1 = min(iz0 + 1, Z - 1);
            size_t g00 = ((size_t)(bX + ix0) * Y + iy0) * Z;
            size_t g01 = ((size_t)(bX + ix0) * Y + iy1) * Z;
            size_t g10 = ((size_t)(bX + ix1) * Y + iy0) * Z;
            size_t g11 = ((size_t)(bX + ix1) * Y + iy1) * Z;
            v000 = vol[g00 + iz0];
            v001 = vol[g00 + iz1];
            v010 = vol[g01 + iz0];
            v011 = vol[g01 + iz1];
            v100 = vol[g10 + iz0];
            v101 = vol[g10 + iz1];
            v110 = vol[g11 + iz0];
            v111 = vol[g11 + iz1];
        }

        // trilinear lerp (z innermost), exact under clamp coincidences
        float c00 = v000 + fz * (v001 - v000);
        float c01 = v010 + fz * (v011 - v010);
        float c10 = v100 + fz * (v101 - v100);
        float c11 = v110 + fz * (v111 - v110);
        float c0  = c00 + fy * (c01 - c00);
        float c1  = c10 + fy * (c11 - c10);
        res[e] = c0 + fx * (c1 - c0);
    }

    f32x4 o;
    o.x = res[0]; o.y = res[1]; o.z = res[2]; o.w = res[3];
    *reinterpret_cast<f32x4*>(out + vid0) = o;
}

extern "C" void kernel_launch(void* const* d_in, const int* in_sizes, int n_in,
                              void* d_out, int out_size, void* d_ws, size_t ws_size,
                              hipStream_t stream) {
    const float* vol = (const float*)d_in[0];
    const float* trf = (const float*)d_in[1];
    float* out = (float*)d_out;

    // allow >64KB dynamic LDS (idempotent, host-side, capture-safe)
    hipFuncSetAttribute(reinterpret_cast<const void*>(warp_kernel),
                        hipFuncAttributeMaxDynamicSharedMemorySize, LDSB);

    warp_kernel<<<NTILES, 1024, LDSB, stream>>>(vol, trf, out);
}

// Round 19
// 40.361 us; speedup vs baseline: 1.2945x; 1.2945x over previous
//
#include <hip/hip_runtime.h>

// vol [2,160,192,160,1] f32, trf [2,160,192,160,3] f32
constexpr int B = 2, X = 160, Y = 192, Z = 160;
constexpr int TXs = 8, TYs = 8, TZs = 16;                // output tile per block (1024 voxels)
constexpr int XT = X / TXs, YT = Y / TYs, ZT = Z / TZs;  // 20, 24, 10
constexpr int NTILES = B * XT * YT * ZT;                 // 9600, divisible by 8
constexpr int NXCD = 8;
constexpr int CHUNK = NTILES / NXCD;                     // 1200
// staged region: x,y halo +-4 (16 slots), z halo +-4 (24)
constexpr int RX = 16, RY = 16, RZ = 24;
constexpr int RSTRIDE = RZ + 1;                          // 25 words (odd): bank spread, pad never read
constexpr int LDSF = RX * RY * RSTRIDE;                  // 6400 floats = 25600 B -> 6 blocks/CU

typedef float f32x4 __attribute__((ext_vector_type(4)));
typedef float f32x2a __attribute__((ext_vector_type(2), aligned(4)));

__global__ __launch_bounds__(256, 6) void warp_kernel(
    const float* __restrict__ vol,
    const float* __restrict__ trf,
    float* __restrict__ out)
{
    __shared__ float lds[LDSF];

    const int tid = threadIdx.x;
    const int bid = blockIdx.x;

    // XCD-chunked bijective swizzle (NTILES % 8 == 0)
    const int eff = (bid & (NXCD - 1)) * CHUNK + (bid >> 3);

    int tz = eff % ZT;
    int r  = eff / ZT;
    int ty = r % YT;
    int r2 = r / YT;
    int tx = r2 % XT;
    int b  = r2 / XT;

    const int xs = tx * TXs - 4;       // region x origin
    const int ys = ty * TYs - 4;       // region y origin
    const int zs = tz * TZs - 4;       // region z origin (multiple of 4)

    // ---- stage vol region into LDS ----
    // 1536 f32x4 chunks: chunk c -> row = c/6 (xi=row>>4, yi=row&15), j = c%6,
    // z = zs+4j (clamped). Thread handles c = tid + 256k; (row,j) advanced
    // incrementally: +256 chunks = +42 rows, j += 4 (mod 6, carry into row).
    {
        int row = (tid * 171) >> 10;       // tid / 6 (exact for tid < 512)
        int j   = tid - 6 * row;
#pragma unroll
        for (int k = 0; k < 6; ++k) {
            int xi = row >> 4;
            int yi = row & 15;
            int xg = min(max(xs + xi, 0), X - 1);
            int yg = min(max(ys + yi, 0), Y - 1);
            int zg = min(max(zs + 4 * j, 0), Z - 4);
            const f32x4 v = *reinterpret_cast<const f32x4*>(
                vol + ((size_t)(b * X + xg) * Y + yg) * Z + zg);
            int a = row * RSTRIDE + 4 * j;
            lds[a + 0] = v.x;
            lds[a + 1] = v.y;
            lds[a + 2] = v.z;
            lds[a + 3] = v.w;
            int jn = j + 4;
            bool wrap = (jn >= 6);
            j   = wrap ? jn - 6 : jn;
            row += wrap ? 43 : 42;
        }
    }
    __syncthreads();

    // ---- this thread's 4 voxels: (x, y, z0v..z0v+3) ----
    int zq = tid & 3;
    int ly = (tid >> 2) & 7;
    int lx = tid >> 5;
    int x  = tx * TXs + lx;
    int y  = ty * TYs + ly;
    int z0v = tz * TZs + 4 * zq;

    size_t vid0 = ((size_t)(b * X + x) * Y + y) * Z + z0v;

    const f32x4* tp = reinterpret_cast<const f32x4*>(trf + vid0 * 3);
    f32x4 t0 = tp[0], t1 = tp[1], t2 = tp[2];
    float d[12] = {t0.x, t0.y, t0.z, t0.w,
                   t1.x, t1.y, t1.z, t1.w,
                   t2.x, t2.y, t2.z, t2.w};

    const float mx = (float)(X - 1), my = (float)(Y - 1), mz = (float)(Z - 1);
    const int bX = b * X;
    const float fxc = (float)x, fyc = (float)y;

    float res[4];
#pragma unroll
    for (int e = 0; e < 4; ++e) {
        float lxf = fxc + d[3 * e + 0];
        float lyf = fyc + d[3 * e + 1];
        float lzf = (float)(z0v + e) + d[3 * e + 2];

        // reference semantics: l0=clip(floor(l),0,max); l1=clip(l0+1,0,max);
        // cl=clip(l,0,max); weight(corner0)=l1-cl; weight(corner1)=1-(l1-cl)
        float lx0 = fminf(fmaxf(floorf(lxf), 0.0f), mx);
        float lx1 = fminf(lx0 + 1.0f, mx);
        float clx = fminf(fmaxf(lxf, 0.0f), mx);
        float wxA = lx1 - clx, wxB = 1.0f - wxA;
        int ix0 = (int)lx0, ix1 = (int)lx1;

        float ly0 = fminf(fmaxf(floorf(lyf), 0.0f), my);
        float ly1 = fminf(ly0 + 1.0f, my);
        float cly = fminf(fmaxf(lyf, 0.0f), my);
        float wyA = ly1 - cly, wyB = 1.0f - wyA;
        int iy0 = (int)ly0, iy1 = (int)ly1;

        float lz0 = fminf(fmaxf(floorf(lzf), 0.0f), mz);
        float lz1 = fminf(lz0 + 1.0f, mz);
        float clz = fminf(fmaxf(lzf, 0.0f), mz);
        float wzA = lz1 - clz, wzB = 1.0f - wzA;
        int iz0 = (int)lz0, iz1 = (int)lz1;

        // z top-edge (iz1==iz0==Z-1): weight moves entirely to corner1; the
        // "+1" LDS slot is then garbage. Flip weights so corner0 (valid slot)
        // carries weight 1 and corner1 is multiplied by 0 (inputs finite).
        bool edge = (iz1 == iz0);
        float wzAe = edge ? 1.0f : wzA;
        float wzBe = edge ? 0.0f : wzB;

        int ux0 = ix0 - xs, uy0 = iy0 - ys, uz0 = iz0 - zs;

        // uz1 = uz0+1 <= RZ-1 iff uz0 < RZ-1; pair-read never touches pad.
        bool ok = ((unsigned)ux0 < (unsigned)RX) & ((unsigned)(ix1 - xs) < (unsigned)RX) &
                  ((unsigned)uy0 < (unsigned)RY) & ((unsigned)(iy1 - ys) < (unsigned)RY) &
                  ((unsigned)uz0 < (unsigned)(RZ - 1));

        float v000, v001, v010, v011, v100, v101, v110, v111;
        if (ok) {
            int dY  = (iy1 > iy0) ? RSTRIDE : 0;
            int dXx = (ix1 > ix0) ? (RSTRIDE * 16) : 0;
            int r00 = ((ux0 << 4) + uy0) * RSTRIDE + uz0;
            int r01 = r00 + dY;
            int r10 = r00 + dXx;
            int r11 = r10 + dY;
            f32x2a p00 = *reinterpret_cast<const f32x2a*>(&lds[r00]);
            f32x2a p01 = *reinterpret_cast<const f32x2a*>(&lds[r01]);
            f32x2a p10 = *reinterpret_cast<const f32x2a*>(&lds[r10]);
            f32x2a p11 = *reinterpret_cast<const f32x2a*>(&lds[r11]);
            v000 = p00.x; v001 = p00.y;
            v010 = p01.x; v011 = p01.y;
            v100 = p10.x; v101 = p10.y;
            v110 = p11.x; v111 = p11.y;
        } else {
            size_t g00 = ((size_t)(bX + ix0) * Y + iy0) * Z;
            size_t g01 = ((size_t)(bX + ix0) * Y + iy1) * Z;
            size_t g10 = ((size_t)(bX + ix1) * Y + iy0) * Z;
            size_t g11 = ((size_t)(bX + ix1) * Y + iy1) * Z;
            v000 = vol[g00 + iz0];
            v001 = vol[g00 + iz1];
            v010 = vol[g01 + iz0];
            v011 = vol[g01 + iz1];
            v100 = vol[g10 + iz0];
            v101 = vol[g10 + iz1];
            v110 = vol[g11 + iz0];
            v111 = vol[g11 + iz1];
        }

        res[e] = wxA * (wyA * (wzAe * v000 + wzBe * v001) +
                        wyB * (wzAe * v010 + wzBe * v011)) +
                 wxB * (wyA * (wzAe * v100 + wzBe * v101) +
                        wyB * (wzAe * v110 + wzBe * v111));
    }

    f32x4 o;
    o.x = res[0]; o.y = res[1]; o.z = res[2]; o.w = res[3];
    *reinterpret_cast<f32x4*>(out + vid0) = o;
}

extern "C" void kernel_launch(void* const* d_in, const int* in_sizes, int n_in,
                              void* d_out, int out_size, void* d_ws, size_t ws_size,
                              hipStream_t stream) {
    const float* vol = (const float*)d_in[0];
    const float* trf = (const float*)d_in[1];
    float* out = (float*)d_out;

    warp_kernel<<<NTILES, 256, 0, stream>>>(vol, trf, out);
}